// Round 3
// baseline (476.251 us; speedup 1.0000x reference)
//
#include <hip/hip_runtime.h>
#include <math.h>

typedef _Float16 f16;
typedef _Float16 f16x8 __attribute__((ext_vector_type(8)));
typedef float f32x4 __attribute__((ext_vector_type(4)));

#define LSEQ 200
#define LT 13       // l-tiles of 16 (chunk space padded to 1792)

// One block per sample n. 256 threads = 4 waves.
// R6: R5 algebra (mappings never round-trip through LDS) + register-pressure fix.
//   R5 spilled to scratch (WRITE_SIZE 667 MB, kernel 238us): acc[13] (52 regs)
//   was live simultaneously with macc[7]+wT+wB. Now:
//   - pack acc->macc PER TILE-PAIR inside the matmul loop (acc liveness 52->8)
//   - wT built after the matmul (only needed in routing loop)
//   Peak liveness ~75 regs -> fits 5 blocks/CU without spill.
// LDS 31696 B -> 5 blocks/CU.
__global__ __launch_bounds__(256, 5)
void capsule_kernel(const float* __restrict__ E,   // [N,200,64]
                    const float* __restrict__ W,   // [64,64]
                    const float* __restrict__ RL,  // [N,3,200]
                    const int* __restrict__ SL,    // [N]
                    float* __restrict__ out)       // [N,3,64]
{
    __shared__ __attribute__((aligned(16))) f16 e_sw[1792*8]; // 28672 B: E A-chunks (read-only after B1)
    __shared__ __attribute__((aligned(16))) f16 w_p[3*224];   //  1344 B: weights, A-frag-permuted layout
    __shared__ __attribute__((aligned(16))) f16 i_c[3*80];    //   480 B: interests rows
    __shared__ __attribute__((aligned(16))) f16 iw_c[3*72];   //   432 B: iW rows (stride 72)
    __shared__ __attribute__((aligned(16))) float cand[192];  //   768 B
    // total 31696 B -> 5 blocks/CU

    const int n = blockIdx.x;
    const int t = threadIdx.x;
    const int lane = t & 63;
    const int wv = t >> 6;
    const int q = lane >> 4;        // quad
    const int cc = lane & 15;       // column within MFMA tile
    const int cmin = cc < 3 ? cc : 2;
    const int o_own = wv*16 + cc;   // this lane's o (and d for the iW exchange)

    // ---- wB: B[k=d][n=o] frags for mappings = E @ W (column gather, L2-hot)
    f16x8 wB[2];
    #pragma unroll
    for (int ks = 0; ks < 2; ks++) {
        f16x8 h;
        #pragma unroll
        for (int j = 0; j < 8; j++) h[j] = (f16)W[(ks*32 + q*8 + j)*64 + o_own];
        wB[ks] = h;
    }

    // ---- initial logits -> registers (owner: lane<16 of wave wv, Tn = wv+4*slot)
    float lg[4][3];
    #pragma unroll
    for (int slot = 0; slot < 4; slot++) {
        int Tn = wv + slot*4;
        if (Tn < LT && lane < 16) {
            int l = Tn*16 + lane;
            if (l < LSEQ) {
                lg[slot][0] = RL[(size_t)n*600 + l];
                lg[slot][1] = RL[(size_t)n*600 + 200 + l];
                lg[slot][2] = RL[(size_t)n*600 + 400 + l];
            }
        }
    }
    const int s = SL[n];

    // ---- zero w_p pad block (all slots of l-pair block p=6, i.e. l in [192,224)).
    //      Valid l=192..199 slots get overwritten by softmax0 after B1.
    if (t < 12) {
        const f16x8 hz = {(f16)0.f,(f16)0.f,(f16)0.f,(f16)0.f,
                          (f16)0.f,(f16)0.f,(f16)0.f,(f16)0.f};
        *(f16x8*)&w_p[(t>>2)*224 + 192 + (t&3)*8] = hz;
    }

    // ---- stage E (fp32 -> f16, A-fragment-swizzled), UNIFORM 7 iters, unrolled.
    const float* Eb = E + (size_t)n * (LSEQ*64);
    const float4 f4z = make_float4(0.f, 0.f, 0.f, 0.f);
    #pragma unroll
    for (int i = 0; i < 7; i++) {
        int g = t + i*256;               // 0..1791, uniform across threads
        int sb = g >> 6, c = g & 63;
        int Tl = sb >> 1, ks = sb & 1;
        int qq = c >> 4, m = c & 15;
        int l = Tl*16 + m;
        int kb = ks*32 + qq*8;
        float4 v0 = f4z, v1 = f4z;
        if (l < LSEQ) {
            v0 = *(const float4*)(Eb + l*64 + kb);
            v1 = *(const float4*)(Eb + l*64 + kb + 4);
        }
        f16x8 h = { (f16)v0.x,(f16)v0.y,(f16)v0.z,(f16)v0.w,
                    (f16)v1.x,(f16)v1.y,(f16)v1.z,(f16)v1.w };
        *(f16x8*)&e_sw[g*8] = h;
    }

    __syncthreads();   // B1

    // ---- main matmul: mappings = E @ W, packed into register B-frags on the fly.
    //      macc[p] covers l-tiles {2p, 2p+1}:
    //      B[k=q*8+j][n=cc] = m[l=(2p + (j>>2))*16 + q*4 + (j&3)][o_own]
    f16x8 macc[7];
    #pragma unroll
    for (int p = 0; p < 6; p++) {
        f32x4 c0 = {0.f, 0.f, 0.f, 0.f};
        f32x4 c1 = {0.f, 0.f, 0.f, 0.f};
        #pragma unroll
        for (int ks = 0; ks < 2; ks++) {
            f16x8 a0 = *(f16x8*)&e_sw[(((2*p  )*2 + ks)*64 + lane)*8];
            c0 = __builtin_amdgcn_mfma_f32_16x16x32_f16(a0, wB[ks], c0, 0, 0, 0);
            f16x8 a1 = *(f16x8*)&e_sw[(((2*p+1)*2 + ks)*64 + lane)*8];
            c1 = __builtin_amdgcn_mfma_f32_16x16x32_f16(a1, wB[ks], c1, 0, 0, 0);
        }
        f16x8 h;
        #pragma unroll
        for (int r = 0; r < 4; r++) { h[r] = (f16)c0[r]; h[4 + r] = (f16)c1[r]; }
        macc[p] = h;
    }
    {
        f32x4 c0 = {0.f, 0.f, 0.f, 0.f};
        #pragma unroll
        for (int ks = 0; ks < 2; ks++) {
            f16x8 a0 = *(f16x8*)&e_sw[((12*2 + ks)*64 + lane)*8];
            c0 = __builtin_amdgcn_mfma_f32_16x16x32_f16(a0, wB[ks], c0, 0, 0, 0);
        }
        f16x8 h;
        #pragma unroll
        for (int r = 0; r < 4; r++) { h[r] = (f16)c0[r]; h[4 + r] = (f16)0.f; }
        macc[6] = h;
    }

    // ---- wT: B[k=o][n=d] frags for iW = i @ W^T (row-contiguous float4 loads).
    //      Built here (not at kernel top) to keep matmul-phase liveness low.
    f16x8 wT[2];
    #pragma unroll
    for (int ks = 0; ks < 2; ks++) {
        const float4 a = *(const float4*)(W + o_own*64 + ks*32 + q*8);
        const float4 b = *(const float4*)(W + o_own*64 + ks*32 + q*8 + 4);
        f16x8 g = { (f16)a.x,(f16)a.y,(f16)a.z,(f16)a.w,
                    (f16)b.x,(f16)b.y,(f16)b.z,(f16)b.w };
        wT[ks] = g;
    }

    // ---- fused softmax0 by logits owners -> w_p (permuted A-frag layout):
    //      slot(l) = (l>>5)*32 + ((l>>2)&3)*8 + ((l>>4)&1)*4 + (l&3)
    #pragma unroll
    for (int slot = 0; slot < 4; slot++) {
        int Tn = wv + slot*4;
        if (Tn < LT && lane < 16) {
            int l = Tn*16 + lane;
            if (l < LSEQ) {
                float w0, w1, w2;
                if (l < s) {
                    float l0 = lg[slot][0], l1 = lg[slot][1], l2 = lg[slot][2];
                    float mx = fmaxf(fmaxf(l0, l1), l2);
                    float e0 = expf(l0 - mx), e1 = expf(l1 - mx), e2 = expf(l2 - mx);
                    float inv = 1.f / (e0 + e1 + e2);
                    w0 = e0*inv; w1 = e1*inv; w2 = e2*inv;
                } else {
                    w0 = w1 = w2 = (1.f/3.f);
                }
                int wbase = (l>>5)*32 + (((l>>2)&3)<<3) + (((l>>4)&1)<<2) + (l&3);
                w_p[wbase]       = (f16)w0;
                w_p[224 + wbase] = (f16)w1;
                w_p[448 + wbase] = (f16)w2;
            }
        }
    }
    __syncthreads();   // B2: w_p ready for cand

    // ---- routing: 3 iterations
    for (int iter = 0; iter < 3; iter++) {
        // cand^T: D[m=caps][n=o_loc] = sum_l w[caps][l] * m[l][o]
        // A = w_p frags (b128 reads, rows 3..15 duplicate caps 2 -> ignored junk),
        // B = macc register frags.
        f32x4 ca = {0.f, 0.f, 0.f, 0.f};
        #pragma unroll
        for (int p = 0; p < 7; p++) {
            f16x8 a = *(f16x8*)&w_p[cmin*224 + p*32 + q*8];
            ca = __builtin_amdgcn_mfma_f32_16x16x32_f16(a, macc[p], ca, 0, 0, 0);
        }
        // D rows 0..2 live in lanes q==0 (r = capsule), col cc = o_loc
        if (q == 0) {
            #pragma unroll
            for (int r = 0; r < 3; r++) cand[r*64 + o_own] = ca[r];
        }
        __syncthreads();

        // squash per capsule k (t<192: k=t>>6, o=t&63), write interests or output
        if (t < 192) {
            float x = cand[t];
            float sq = x*x;
            #pragma unroll
            for (int off = 32; off >= 1; off >>= 1) sq += __shfl_xor(sq, off, 64);
            float factor = sq / ((1.f + sq) * sqrtf(sq + 1e-8f));
            float y = factor * x;
            if (iter < 2) {
                i_c[(t >> 6)*80 + (t & 63)] = (f16)y;
            } else {
                out[(size_t)n*192 + t] = y;
            }
        }
        if (iter == 2) break;
        __syncthreads();

        // iW[k][d] = sum_o i[k][o] * W[d][o]: A = i_c frags, B = wT regs.
        // D[m=caps][n=d_loc]; wave wv owns d-tile wv.
        {
            f16x8 ia0 = *(f16x8*)&i_c[cmin*80 + q*8];
            f16x8 ia1 = *(f16x8*)&i_c[cmin*80 + 32 + q*8];
            f32x4 dw = {0.f, 0.f, 0.f, 0.f};
            dw = __builtin_amdgcn_mfma_f32_16x16x32_f16(ia0, wT[0], dw, 0, 0, 0);
            dw = __builtin_amdgcn_mfma_f32_16x16x32_f16(ia1, wT[1], dw, 0, 0, 0);
            if (q == 0) {
                #pragma unroll
                for (int r = 0; r < 3; r++) iw_c[r*72 + o_own] = (f16)dw[r];
            }
        }
        __syncthreads();   // iw_c exchange complete

        // delta: logits[k][l] += sum_d iW[k][d] * E[l][d]; fused next-softmax.
        // A = iw_c frags, B = ORIGINAL staged E chunks (b128, conflict-free).
        f16x8 iwa0 = *(f16x8*)&iw_c[cmin*72 + q*8];
        f16x8 iwa1 = *(f16x8*)&iw_c[cmin*72 + 32 + q*8];
        #pragma unroll
        for (int slot = 0; slot < 4; slot++) {
            int Tn = wv + slot*4;
            if (Tn < LT) {
                f32x4 da = {0.f, 0.f, 0.f, 0.f};
                f16x8 b0 = *(f16x8*)&e_sw[((Tn*2 + 0)*64 + lane)*8];
                da = __builtin_amdgcn_mfma_f32_16x16x32_f16(iwa0, b0, da, 0, 0, 0);
                f16x8 b1 = *(f16x8*)&e_sw[((Tn*2 + 1)*64 + lane)*8];
                da = __builtin_amdgcn_mfma_f32_16x16x32_f16(iwa1, b1, da, 0, 0, 0);
                if (lane < 16) {
                    int l = Tn*16 + lane;
                    if (l < LSEQ) {
                        float w0, w1, w2;
                        if (l < s) {
                            float l0 = lg[slot][0] + da[0];
                            float l1 = lg[slot][1] + da[1];
                            float l2 = lg[slot][2] + da[2];
                            lg[slot][0] = l0; lg[slot][1] = l1; lg[slot][2] = l2;
                            float mx = fmaxf(fmaxf(l0, l1), l2);
                            float e0 = expf(l0 - mx), e1 = expf(l1 - mx), e2 = expf(l2 - mx);
                            float inv = 1.f / (e0 + e1 + e2);
                            w0 = e0*inv; w1 = e1*inv; w2 = e2*inv;
                        } else {
                            w0 = w1 = w2 = (1.f/3.f);
                        }
                        int wbase = (l>>5)*32 + (((l>>2)&3)<<3) + (((l>>4)&1)<<2) + (l&3);
                        w_p[wbase]       = (f16)w0;
                        w_p[224 + wbase] = (f16)w1;
                        w_p[448 + wbase] = (f16)w2;
                    }
                }
            }
        }
        __syncthreads();
    }
}

extern "C" void kernel_launch(void* const* d_in, const int* in_sizes, int n_in,
                              void* d_out, int out_size, void* d_ws, size_t ws_size,
                              hipStream_t stream) {
    const float* E  = (const float*)d_in[0];
    const float* W  = (const float*)d_in[1];
    const float* RL = (const float*)d_in[2];
    const int*   SL = (const int*)d_in[3];
    float* o = (float*)d_out;
    const int N = in_sizes[3];   // seq_len has N entries
    capsule_kernel<<<dim3(N), dim3(256), 0, stream>>>(E, W, RL, SL, o);
}

// Round 4
// 302.111 us; speedup vs baseline: 1.5764x; 1.5764x over previous
//
#include <hip/hip_runtime.h>
#include <math.h>

typedef _Float16 f16;
typedef _Float16 f16x8 __attribute__((ext_vector_type(8)));
typedef float f32x4 __attribute__((ext_vector_type(4)));

#define LSEQ 200
#define LT 13       // l-tiles of 16 (chunk space padded to 1792)

// One block per sample n. 256 threads = 4 waves.
// R7: R5/R6 algebra, scratch-demotion fix.
//   R5/R6 showed VGPR_Count=48 + ~730B/thread scratch writes (WRITE_SIZE 667-764MB)
//   -> compiler demoted the f16x8 arrays to scratch despite static indexing.
//   Fix: (a) ALL persistent fragment arrays replaced by NAMED variables
//   (mc0..mc6, wB0/1, wt0/1) with hand-unrolled uses; (b) launch_bounds(256,4)
//   raises the VGPR cap to ~128 (occupancy was already ~4 blocks/CU).
// LDS 31696 B.
__global__ __launch_bounds__(256, 4)
void capsule_kernel(const float* __restrict__ E,   // [N,200,64]
                    const float* __restrict__ W,   // [64,64]
                    const float* __restrict__ RL,  // [N,3,200]
                    const int* __restrict__ SL,    // [N]
                    float* __restrict__ out)       // [N,3,64]
{
    __shared__ __attribute__((aligned(16))) f16 e_sw[1792*8]; // 28672 B: E A-chunks (read-only after B1)
    __shared__ __attribute__((aligned(16))) f16 w_p[3*224];   //  1344 B: weights, A-frag-permuted layout
    __shared__ __attribute__((aligned(16))) f16 i_c[3*80];    //   480 B: interests rows
    __shared__ __attribute__((aligned(16))) f16 iw_c[3*72];   //   432 B: iW rows (stride 72)
    __shared__ __attribute__((aligned(16))) float cand[192];  //   768 B

    const int n = blockIdx.x;
    const int t = threadIdx.x;
    const int lane = t & 63;
    const int wv = t >> 6;
    const int q = lane >> 4;        // quad
    const int cc = lane & 15;       // column within MFMA tile
    const int cmin = cc < 3 ? cc : 2;
    const int o_own = wv*16 + cc;   // this lane's o (and d for the iW exchange)

    // ---- wB: B[k=d][n=o] frags for mappings = E @ W (column gather, L2-hot)
    f16x8 wB0, wB1;
    {
        f16x8 h;
        #pragma unroll
        for (int j = 0; j < 8; j++) h[j] = (f16)W[(q*8 + j)*64 + o_own];
        wB0 = h;
        #pragma unroll
        for (int j = 0; j < 8; j++) h[j] = (f16)W[(32 + q*8 + j)*64 + o_own];
        wB1 = h;
    }

    // ---- initial logits -> registers (owner: lane<16 of wave wv, Tn = wv+4*slot)
    float lg[4][3];
    #pragma unroll
    for (int slot = 0; slot < 4; slot++) {
        int Tn = wv + slot*4;
        if (Tn < LT && lane < 16) {
            int l = Tn*16 + lane;
            if (l < LSEQ) {
                lg[slot][0] = RL[(size_t)n*600 + l];
                lg[slot][1] = RL[(size_t)n*600 + 200 + l];
                lg[slot][2] = RL[(size_t)n*600 + 400 + l];
            }
        }
    }
    const int s = SL[n];

    // ---- zero w_p pad block (all slots of l-pair block p=6, i.e. l in [192,224)).
    //      Valid l=192..199 slots get overwritten by softmax0 after B1.
    if (t < 12) {
        const f16x8 hz = {(f16)0.f,(f16)0.f,(f16)0.f,(f16)0.f,
                          (f16)0.f,(f16)0.f,(f16)0.f,(f16)0.f};
        *(f16x8*)&w_p[(t>>2)*224 + 192 + (t&3)*8] = hz;
    }

    // ---- stage E (fp32 -> f16, A-fragment-swizzled), UNIFORM 7 iters, unrolled.
    const float* Eb = E + (size_t)n * (LSEQ*64);
    const float4 f4z = make_float4(0.f, 0.f, 0.f, 0.f);
    #pragma unroll
    for (int i = 0; i < 7; i++) {
        int g = t + i*256;               // 0..1791, uniform across threads
        int sb = g >> 6, c = g & 63;
        int Tl = sb >> 1, ks = sb & 1;
        int qq = c >> 4, m = c & 15;
        int l = Tl*16 + m;
        int kb = ks*32 + qq*8;
        float4 v0 = f4z, v1 = f4z;
        if (l < LSEQ) {
            v0 = *(const float4*)(Eb + l*64 + kb);
            v1 = *(const float4*)(Eb + l*64 + kb + 4);
        }
        f16x8 h = { (f16)v0.x,(f16)v0.y,(f16)v0.z,(f16)v0.w,
                    (f16)v1.x,(f16)v1.y,(f16)v1.z,(f16)v1.w };
        *(f16x8*)&e_sw[g*8] = h;
    }

    __syncthreads();   // B1

    // ---- main matmul: mappings = E @ W, packed into NAMED register B-frags.
    //      mcP covers l-tiles {2P, 2P+1}:
    //      B[k=q*8+j][n=cc] = m[l=(2P + (j>>2))*16 + q*4 + (j&3)][o_own]
    f16x8 mc0, mc1, mc2, mc3, mc4, mc5, mc6;

#define MM_PAIR(P, MC)                                                        \
    {                                                                         \
        f32x4 c0 = {0.f, 0.f, 0.f, 0.f};                                      \
        f32x4 c1 = {0.f, 0.f, 0.f, 0.f};                                      \
        f16x8 a00 = *(f16x8*)&e_sw[(((2*(P)  )*2 + 0)*64 + lane)*8];          \
        c0 = __builtin_amdgcn_mfma_f32_16x16x32_f16(a00, wB0, c0, 0, 0, 0);   \
        f16x8 a01 = *(f16x8*)&e_sw[(((2*(P)  )*2 + 1)*64 + lane)*8];          \
        c0 = __builtin_amdgcn_mfma_f32_16x16x32_f16(a01, wB1, c0, 0, 0, 0);   \
        f16x8 a10 = *(f16x8*)&e_sw[(((2*(P)+1)*2 + 0)*64 + lane)*8];          \
        c1 = __builtin_amdgcn_mfma_f32_16x16x32_f16(a10, wB0, c1, 0, 0, 0);   \
        f16x8 a11 = *(f16x8*)&e_sw[(((2*(P)+1)*2 + 1)*64 + lane)*8];          \
        c1 = __builtin_amdgcn_mfma_f32_16x16x32_f16(a11, wB1, c1, 0, 0, 0);   \
        f16x8 hh;                                                             \
        hh[0]=(f16)c0[0]; hh[1]=(f16)c0[1]; hh[2]=(f16)c0[2]; hh[3]=(f16)c0[3];\
        hh[4]=(f16)c1[0]; hh[5]=(f16)c1[1]; hh[6]=(f16)c1[2]; hh[7]=(f16)c1[3];\
        MC = hh;                                                              \
    }

    MM_PAIR(0, mc0)
    MM_PAIR(1, mc1)
    MM_PAIR(2, mc2)
    MM_PAIR(3, mc3)
    MM_PAIR(4, mc4)
    MM_PAIR(5, mc5)
#undef MM_PAIR
    {   // tail: l-tile 12 only, high half zero
        f32x4 c0 = {0.f, 0.f, 0.f, 0.f};
        f16x8 a00 = *(f16x8*)&e_sw[((12*2 + 0)*64 + lane)*8];
        c0 = __builtin_amdgcn_mfma_f32_16x16x32_f16(a00, wB0, c0, 0, 0, 0);
        f16x8 a01 = *(f16x8*)&e_sw[((12*2 + 1)*64 + lane)*8];
        c0 = __builtin_amdgcn_mfma_f32_16x16x32_f16(a01, wB1, c0, 0, 0, 0);
        f16x8 hh;
        hh[0]=(f16)c0[0]; hh[1]=(f16)c0[1]; hh[2]=(f16)c0[2]; hh[3]=(f16)c0[3];
        hh[4]=(f16)0.f;   hh[5]=(f16)0.f;   hh[6]=(f16)0.f;   hh[7]=(f16)0.f;
        mc6 = hh;
    }

    // ---- wt: B[k=o][n=d] frags for iW = i @ W^T (row-contiguous float4 loads).
    //      Built after the matmul to keep matmul-phase liveness low.
    f16x8 wt0, wt1;
    {
        const float4 a0 = *(const float4*)(W + o_own*64 + q*8);
        const float4 b0 = *(const float4*)(W + o_own*64 + q*8 + 4);
        f16x8 g0 = { (f16)a0.x,(f16)a0.y,(f16)a0.z,(f16)a0.w,
                     (f16)b0.x,(f16)b0.y,(f16)b0.z,(f16)b0.w };
        wt0 = g0;
        const float4 a1 = *(const float4*)(W + o_own*64 + 32 + q*8);
        const float4 b1 = *(const float4*)(W + o_own*64 + 32 + q*8 + 4);
        f16x8 g1 = { (f16)a1.x,(f16)a1.y,(f16)a1.z,(f16)a1.w,
                     (f16)b1.x,(f16)b1.y,(f16)b1.z,(f16)b1.w };
        wt1 = g1;
    }

    // ---- fused softmax0 by logits owners -> w_p (permuted A-frag layout):
    //      slot(l) = (l>>5)*32 + ((l>>2)&3)*8 + ((l>>4)&1)*4 + (l&3)
    #pragma unroll
    for (int slot = 0; slot < 4; slot++) {
        int Tn = wv + slot*4;
        if (Tn < LT && lane < 16) {
            int l = Tn*16 + lane;
            if (l < LSEQ) {
                float w0, w1, w2;
                if (l < s) {
                    float l0 = lg[slot][0], l1 = lg[slot][1], l2 = lg[slot][2];
                    float mx = fmaxf(fmaxf(l0, l1), l2);
                    float e0 = expf(l0 - mx), e1 = expf(l1 - mx), e2 = expf(l2 - mx);
                    float inv = 1.f / (e0 + e1 + e2);
                    w0 = e0*inv; w1 = e1*inv; w2 = e2*inv;
                } else {
                    w0 = w1 = w2 = (1.f/3.f);
                }
                int wbase = (l>>5)*32 + (((l>>2)&3)<<3) + (((l>>4)&1)<<2) + (l&3);
                w_p[wbase]       = (f16)w0;
                w_p[224 + wbase] = (f16)w1;
                w_p[448 + wbase] = (f16)w2;
            }
        }
    }
    __syncthreads();   // B2: w_p ready for cand

    // ---- routing: 3 iterations
    for (int iter = 0; iter < 3; iter++) {
        // cand^T: D[m=caps][n=o_loc] = sum_l w[caps][l] * m[l][o]
        // A = w_p frags (b128 reads, rows 3..15 duplicate caps 2 -> ignored junk),
        // B = named mc register frags.
        f32x4 ca = {0.f, 0.f, 0.f, 0.f};
#define CAND_STEP(P, MC)                                                      \
        { f16x8 a = *(f16x8*)&w_p[cmin*224 + (P)*32 + q*8];                   \
          ca = __builtin_amdgcn_mfma_f32_16x16x32_f16(a, MC, ca, 0, 0, 0); }
        CAND_STEP(0, mc0)
        CAND_STEP(1, mc1)
        CAND_STEP(2, mc2)
        CAND_STEP(3, mc3)
        CAND_STEP(4, mc4)
        CAND_STEP(5, mc5)
        CAND_STEP(6, mc6)
#undef CAND_STEP
        // D rows 0..2 live in lanes q==0 (r = capsule), col cc = o_loc
        if (q == 0) {
            cand[0*64 + o_own] = ca[0];
            cand[1*64 + o_own] = ca[1];
            cand[2*64 + o_own] = ca[2];
        }
        __syncthreads();

        // squash per capsule k (t<192: k=t>>6, o=t&63), write interests or output
        if (t < 192) {
            float x = cand[t];
            float sq = x*x;
            #pragma unroll
            for (int off = 32; off >= 1; off >>= 1) sq += __shfl_xor(sq, off, 64);
            float factor = sq / ((1.f + sq) * sqrtf(sq + 1e-8f));
            float y = factor * x;
            if (iter < 2) {
                i_c[(t >> 6)*80 + (t & 63)] = (f16)y;
            } else {
                out[(size_t)n*192 + t] = y;
            }
        }
        if (iter == 2) break;
        __syncthreads();

        // iW[k][d] = sum_o i[k][o] * W[d][o]: A = i_c frags, B = wt regs.
        // D[m=caps][n=d_loc]; wave wv owns d-tile wv.
        {
            f16x8 ia0 = *(f16x8*)&i_c[cmin*80 + q*8];
            f16x8 ia1 = *(f16x8*)&i_c[cmin*80 + 32 + q*8];
            f32x4 dw = {0.f, 0.f, 0.f, 0.f};
            dw = __builtin_amdgcn_mfma_f32_16x16x32_f16(ia0, wt0, dw, 0, 0, 0);
            dw = __builtin_amdgcn_mfma_f32_16x16x32_f16(ia1, wt1, dw, 0, 0, 0);
            if (q == 0) {
                iw_c[0*72 + o_own] = (f16)dw[0];
                iw_c[1*72 + o_own] = (f16)dw[1];
                iw_c[2*72 + o_own] = (f16)dw[2];
            }
        }
        __syncthreads();   // iw_c exchange complete

        // delta: logits[k][l] += sum_d iW[k][d] * E[l][d]; fused next-softmax.
        // A = iw_c frags, B = ORIGINAL staged E chunks (b128, conflict-free).
        f16x8 iwa0 = *(f16x8*)&iw_c[cmin*72 + q*8];
        f16x8 iwa1 = *(f16x8*)&iw_c[cmin*72 + 32 + q*8];
        #pragma unroll
        for (int slot = 0; slot < 4; slot++) {
            int Tn = wv + slot*4;
            if (Tn < LT) {
                f32x4 da = {0.f, 0.f, 0.f, 0.f};
                f16x8 b0 = *(f16x8*)&e_sw[((Tn*2 + 0)*64 + lane)*8];
                da = __builtin_amdgcn_mfma_f32_16x16x32_f16(iwa0, b0, da, 0, 0, 0);
                f16x8 b1 = *(f16x8*)&e_sw[((Tn*2 + 1)*64 + lane)*8];
                da = __builtin_amdgcn_mfma_f32_16x16x32_f16(iwa1, b1, da, 0, 0, 0);
                if (lane < 16) {
                    int l = Tn*16 + lane;
                    if (l < LSEQ) {
                        float w0, w1, w2;
                        if (l < s) {
                            float l0 = lg[slot][0] + da[0];
                            float l1 = lg[slot][1] + da[1];
                            float l2 = lg[slot][2] + da[2];
                            lg[slot][0] = l0; lg[slot][1] = l1; lg[slot][2] = l2;
                            float mx = fmaxf(fmaxf(l0, l1), l2);
                            float e0 = expf(l0 - mx), e1 = expf(l1 - mx), e2 = expf(l2 - mx);
                            float inv = 1.f / (e0 + e1 + e2);
                            w0 = e0*inv; w1 = e1*inv; w2 = e2*inv;
                        } else {
                            w0 = w1 = w2 = (1.f/3.f);
                        }
                        int wbase = (l>>5)*32 + (((l>>2)&3)<<3) + (((l>>4)&1)<<2) + (l&3);
                        w_p[wbase]       = (f16)w0;
                        w_p[224 + wbase] = (f16)w1;
                        w_p[448 + wbase] = (f16)w2;
                    }
                }
            }
        }
        __syncthreads();
    }
}

extern "C" void kernel_launch(void* const* d_in, const int* in_sizes, int n_in,
                              void* d_out, int out_size, void* d_ws, size_t ws_size,
                              hipStream_t stream) {
    const float* E  = (const float*)d_in[0];
    const float* W  = (const float*)d_in[1];
    const float* RL = (const float*)d_in[2];
    const int*   SL = (const int*)d_in[3];
    float* o = (float*)d_out;
    const int N = in_sizes[3];   // seq_len has N entries
    capsule_kernel<<<dim3(N), dim3(256), 0, stream>>>(E, W, RL, SL, o);
}